// Round 1
// baseline (58.316 us; speedup 1.0000x reference)
//
#include <hip/hip_runtime.h>
#include <math.h>

// Problem constants (fixed by setup_inputs)
constexpr int B_ = 16, S_ = 512, T_ = 4096, E_ = 256;
constexpr int DUR = T_ / S_;           // 8
constexpr int M_ENC = B_ * S_;         // 8192 rows of enc@W
constexpr int M_TOT = M_ENC + T_;      // + 4096 rows of PE@W = 12288

// Workspace layout (bytes); total ~16.8 MB
constexpr size_t IDX_OFF  = 0;                              // B*T int32 = 256KB
constexpr size_t FLAG_OFF = (size_t)B_ * T_ * 4;            // 4 bytes
constexpr size_t PE_OFF   = 512 * 1024;                     // T*E f32 = 4MB
constexpr size_t EW_OFF   = PE_OFF + (size_t)T_ * E_ * 4;   // B*S*E f32 = 8MB
constexpr size_t PEW_OFF  = EW_OFF + (size_t)M_ENC * E_ * 4;// T*E f32 = 4MB

// ---------------------------------------------------------------------------
// Kernel 1: sinusoidal PE table [T, E]; also zero the fallback flag.
__global__ void k_pe(float* __restrict__ pe, int* __restrict__ flag) {
    const int t = blockIdx.x;
    const int j = threadIdx.x;              // pair index 0..127
    if (t == 0 && j == 0) *flag = 0;
    const float NEGC = -(float)(9.210340371976184 / (double)E_); // -ln(10000)/E
    float d = expf((float)(2 * j) * NEGC);
    float arg = (float)t * d;
    float s, c;
    sincosf(arg, &s, &c);
    pe[(size_t)t * E_ + 2 * j]     = s;
    pe[(size_t)t * E_ + 2 * j + 1] = c;
}

// ---------------------------------------------------------------------------
// Kernel 2: write closed-form aligner index candidate and validate the scan
// recurrence fully in parallel. Any violation sets *flag.
__global__ void k_check(const int* __restrict__ align, const int* __restrict__ text,
                        int* __restrict__ idx, int* __restrict__ flag) {
    const int id = blockIdx.x * 256 + threadIdx.x;   // < B*T
    const int b = id / T_;
    const int t = id % T_;
    const int cand = t / DUR;
    idx[id] = cand;
    if (t > 0) {
        const int prev = (t - 1) / DUR;
        const int a = align[id];
        const int expct = (a == text[b * S_ + prev]) ? prev : min(prev + 1, S_ - 1);
        if (cand != expct) atomicOr(flag, 1);
    }
}

// Kernel 3: serial fallback — only runs if the candidate failed validation.
__global__ void k_fallback(const int* __restrict__ align, const int* __restrict__ text,
                           int* __restrict__ idx, const int* __restrict__ flag) {
    if (*flag == 0) return;
    const int b = threadIdx.x;
    if (b >= B_) return;
    int i = 0;
    idx[b * T_] = 0;
    for (int t = 1; t < T_; ++t) {
        const int a = align[b * T_ + t];
        if (a != text[b * S_ + i]) i = min(i + 1, S_ - 1);
        idx[b * T_ + t] = i;
    }
}

// ---------------------------------------------------------------------------
// Kernel 4: fp32 tiled GEMM, [12288 x 256] @ [256 x 256].
// Rows < M_ENC come from enc -> EW (no bias); rows >= M_ENC from PE -> PEW (+b_pos).
// BM=BN=64, BK=32, 256 threads, 4x4 micro-tile per thread.
__global__ __launch_bounds__(256) void k_gemm(
    const float* __restrict__ enc, const float* __restrict__ pe,
    const float* __restrict__ W, const float* __restrict__ bias,
    float* __restrict__ ew, float* __restrict__ pew)
{
    __shared__ float As[32][64];   // k-major: As[kk][m]
    __shared__ float Bs[32][64];   // Bs[kk][n]

    const int tid  = threadIdx.x;
    const int n0   = blockIdx.x * 64;
    const int m0   = blockIdx.y * 64;
    const bool isPE = (m0 >= M_ENC);
    const float* A = isPE ? (pe + (size_t)(m0 - M_ENC) * E_) : (enc + (size_t)m0 * E_);

    const int wid  = tid >> 6;          // 0..3
    const int lane = tid & 63;
    const int arow = lane;              // A tile row
    const int ak   = wid * 8;           // A tile col-group base (8 cols per wave)
    const int bk   = tid >> 4;          // 0..15 (+16 second pass) B tile row
    const int bn   = (tid & 15) * 4;    // B tile col (float4)
    const int tm   = (tid >> 4) * 4;    // output micro-tile row base
    const int tn   = (tid & 15) * 4;    // output micro-tile col base

    float acc[4][4] = {{0.f}};

    for (int k0 = 0; k0 < E_; k0 += 32) {
        float4 a0 = *(const float4*)(A + (size_t)arow * E_ + k0 + ak);
        float4 a1 = *(const float4*)(A + (size_t)arow * E_ + k0 + ak + 4);
        float4 b0 = *(const float4*)(W + (size_t)(k0 + bk)      * E_ + n0 + bn);
        float4 b1 = *(const float4*)(W + (size_t)(k0 + bk + 16) * E_ + n0 + bn);
        __syncthreads();
        As[ak + 0][arow] = a0.x; As[ak + 1][arow] = a0.y;
        As[ak + 2][arow] = a0.z; As[ak + 3][arow] = a0.w;
        As[ak + 4][arow] = a1.x; As[ak + 5][arow] = a1.y;
        As[ak + 6][arow] = a1.z; As[ak + 7][arow] = a1.w;
        *(float4*)&Bs[bk][bn]      = b0;
        *(float4*)&Bs[bk + 16][bn] = b1;
        __syncthreads();
#pragma unroll
        for (int kk = 0; kk < 32; ++kk) {
            const float4 av = *(const float4*)&As[kk][tm];
            const float4 bv = *(const float4*)&Bs[kk][tn];
            acc[0][0] += av.x * bv.x; acc[0][1] += av.x * bv.y;
            acc[0][2] += av.x * bv.z; acc[0][3] += av.x * bv.w;
            acc[1][0] += av.y * bv.x; acc[1][1] += av.y * bv.y;
            acc[1][2] += av.y * bv.z; acc[1][3] += av.y * bv.w;
            acc[2][0] += av.z * bv.x; acc[2][1] += av.z * bv.y;
            acc[2][2] += av.z * bv.z; acc[2][3] += av.z * bv.w;
            acc[3][0] += av.w * bv.x; acc[3][1] += av.w * bv.y;
            acc[3][2] += av.w * bv.z; acc[3][3] += av.w * bv.w;
        }
    }

    float4 bi = make_float4(0.f, 0.f, 0.f, 0.f);
    if (isPE) bi = *(const float4*)(bias + n0 + tn);
#pragma unroll
    for (int i2 = 0; i2 < 4; ++i2) {
        const int row = m0 + tm + i2;
        float4 o = make_float4(acc[i2][0] + bi.x, acc[i2][1] + bi.y,
                               acc[i2][2] + bi.z, acc[i2][3] + bi.w);
        if (isPE) *(float4*)(pew + (size_t)(row - M_ENC) * E_ + n0 + tn) = o;
        else      *(float4*)(ew  + (size_t)row            * E_ + n0 + tn) = o;
    }
}

// ---------------------------------------------------------------------------
// Kernel 5: fused epilogue.
// out[b,t,:] = enc[b,i,:] + EW[b,i,:] + PEW[t,:] + pitch*W_pitch + b_pitch + emb_beats[beat]
__global__ __launch_bounds__(256) void k_final(
    const float* __restrict__ enc, const float* __restrict__ ew,
    const float* __restrict__ pew, const int* __restrict__ idx,
    const float* __restrict__ pitch, const int* __restrict__ beats,
    const float* __restrict__ wpitch, const float* __restrict__ bpitch,
    const float* __restrict__ embb, float* __restrict__ out)
{
    const int tid = threadIdx.x;
    const int r = tid >> 6;                 // row within block (0..3)
    const int c = tid & 63;                 // float4 lane within row
    const int row = blockIdx.x * 4 + r;     // = b*T + t
    const int b = row / T_;
    const int t = row % T_;
    const int i = idx[row];                 // uniform per wave
    const float p = pitch[row];
    const int bt = beats[row];

    const size_t grow = (size_t)(b * S_ + i) * E_ + c * 4;
    const float4 e4 = *(const float4*)(enc + grow);
    const float4 w4 = *(const float4*)(ew + grow);
    const float4 q4 = *(const float4*)(pew + (size_t)t * E_ + c * 4);
    const float4 wp = *(const float4*)(wpitch + c * 4);
    const float4 bp = *(const float4*)(bpitch + c * 4);
    const float4 be = *(const float4*)(embb + (size_t)bt * E_ + c * 4);

    float4 o;
    o.x = e4.x + w4.x + q4.x + p * wp.x + bp.x + be.x;
    o.y = e4.y + w4.y + q4.y + p * wp.y + bp.y + be.y;
    o.z = e4.z + w4.z + q4.z + p * wp.z + bp.z + be.z;
    o.w = e4.w + w4.w + q4.w + p * wp.w + bp.w + be.w;
    *(float4*)(out + (size_t)row * E_ + c * 4) = o;
}

// ---------------------------------------------------------------------------
extern "C" void kernel_launch(void* const* d_in, const int* in_sizes, int n_in,
                              void* d_out, int out_size, void* d_ws, size_t ws_size,
                              hipStream_t stream) {
    const float* enc    = (const float*)d_in[0];
    const int*   align  = (const int*)  d_in[1];
    const int*   text   = (const int*)  d_in[2];
    const float* pitch  = (const float*)d_in[3];
    const int*   beats  = (const int*)  d_in[4];
    const float* wpitch = (const float*)d_in[5];
    const float* bpitch = (const float*)d_in[6];
    const float* embb   = (const float*)d_in[7];
    const float* wpos   = (const float*)d_in[8];
    const float* bpos   = (const float*)d_in[9];
    float* out = (float*)d_out;

    char* ws = (char*)d_ws;
    int*   idx  = (int*)  (ws + IDX_OFF);
    int*   flag = (int*)  (ws + FLAG_OFF);
    float* pe   = (float*)(ws + PE_OFF);
    float* ewb  = (float*)(ws + EW_OFF);
    float* pewb = (float*)(ws + PEW_OFF);

    hipLaunchKernelGGL(k_pe, dim3(T_), dim3(E_ / 2), 0, stream, pe, flag);
    hipLaunchKernelGGL(k_check, dim3(B_ * T_ / 256), dim3(256), 0, stream,
                       align, text, idx, flag);
    hipLaunchKernelGGL(k_fallback, dim3(1), dim3(64), 0, stream,
                       align, text, idx, flag);
    hipLaunchKernelGGL(k_gemm, dim3(E_ / 64, M_TOT / 64), dim3(256), 0, stream,
                       enc, pe, wpos, bpos, ewb, pewb);
    hipLaunchKernelGGL(k_final, dim3(B_ * T_ / 4), dim3(256), 0, stream,
                       enc, ewb, pewb, idx, pitch, beats, wpitch, bpitch, embb, out);
}

// Round 2
// 38.772 us; speedup vs baseline: 1.5041x; 1.5041x over previous
//
#include <hip/hip_runtime.h>
#include <hip/hip_bf16.h>
#include <math.h>

// Problem constants (fixed by setup_inputs)
constexpr int B_ = 16, S_ = 512, T_ = 4096, E_ = 256;
constexpr int M_ENC = B_ * S_;   // 8192

typedef __attribute__((ext_vector_type(8))) short short8;
typedef __attribute__((ext_vector_type(4))) float f32x4;

// Workspace layout (bytes), total 15 MB
constexpr size_t FLAG_OFF = 0;
constexpr size_t IDX_OFF  = 4096;                 // B*T int32 = 256KB
constexpr size_t WT_OFF   = 512u * 1024;          // 256x256 bf16 (W^T) = 128KB
constexpr size_t PEBF_OFF = 1024u * 1024;         // 4096x256 bf16 PE = 2MB
constexpr size_t PEW_OFF  = 3u * 1024 * 1024;     // 4096x256 f32 = 4MB
constexpr size_t EWP_OFF  = 7u * 1024 * 1024;     // 8192x256 f32 = 8MB (fallback only)

// RNE fp32 -> bf16 bits (no NaN in this data)
__device__ __forceinline__ short bf16s(float x) {
    unsigned u = __float_as_uint(x);
    u += 0x7FFFu + ((u >> 16) & 1u);
    return (short)(u >> 16);
}

// ---------------------------------------------------------------------------
// Prep kernel, roles by blockIdx.x:
//  [0,256)    : closed-form aligner idx + parallel validation of the scan
//  [256,272)  : W^T -> bf16 (WT[n][k] = W[k][n])
//  [272,2320) : sinusoidal PE table as bf16 [T][E]
__global__ __launch_bounds__(256) void k_prep(
    const int* __restrict__ align, const int* __restrict__ text,
    const float* __restrict__ W,
    int* __restrict__ idx, int* __restrict__ flag,
    short* __restrict__ wt, unsigned int* __restrict__ pe2)
{
    const int bid = blockIdx.x, tid = threadIdx.x;
    if (bid < 256) {
        const int id = bid * 256 + tid;          // < B*T
        const int b = id / T_, t = id % T_;
        const int cand = t >> 3;                 // DUR = 8
        idx[id] = cand;
        if (t > 0) {
            const int prev = (t - 1) >> 3;
            const int a = align[id];
            const int expct = (a == text[b * S_ + prev]) ? prev : min(prev + 1, S_ - 1);
            if (cand != expct) atomicOr(flag, 1);
        }
    } else if (bid < 272) {
        const int kb = (bid - 256) * 16;
        short8 v0, v1;
#pragma unroll
        for (int j = 0; j < 8; ++j) v0[j] = bf16s(W[(kb + j) * E_ + tid]);
#pragma unroll
        for (int j = 0; j < 8; ++j) v1[j] = bf16s(W[(kb + 8 + j) * E_ + tid]);
        *(short8*)(wt + tid * E_ + kb)     = v0;
        *(short8*)(wt + tid * E_ + kb + 8) = v1;
    } else {
        const int p = bid - 272;                 // 0..2047
        const int t = p * 2 + (tid >> 7);
        const int j = tid & 127;
        const float NEGC = -3.5977077674865723e-2f;  // -ln(10000)/256
        float d = expf((float)(2 * j) * NEGC);
        float s, c;
        sincosf((float)t * d, &s, &c);
        unsigned us = (unsigned short)bf16s(s);
        unsigned uc = (unsigned short)bf16s(c);
        pe2[t * 128 + j] = us | (uc << 16);
    }
}

// Serial fallback (only if validation failed — never for this data)
__global__ void k_fallback(const int* __restrict__ align, const int* __restrict__ text,
                           int* __restrict__ idx, const int* __restrict__ flag) {
    if (*flag == 0) return;
    const int b = threadIdx.x;
    if (b >= B_) return;
    int i = 0;
    idx[b * T_] = 0;
    for (int t = 1; t < T_; ++t) {
        if (align[b * T_ + t] != text[b * S_ + i]) i = min(i + 1, S_ - 1);
        idx[b * T_ + t] = i;
    }
}

// ---------------------------------------------------------------------------
// bf16 MFMA GEMM core. Tile 64(M) x 64(N) x full K=256, 4 waves (2x2 of 32x32).
// MODE 0: A = PE(bf16) -> pew_out = A@W + b_pos
// MODE 1: A = enc(f32->bf16); epilogue expands each row into its 8 output rows:
//         out[b, i*8+d] = enc + acc + pew[t] + pitch*Wp + bp + emb_beats[beat]
//         (fallback flag path writes ewp = enc + acc instead)
template <int MODE>
__global__ __launch_bounds__(256) void k_gemm(
    const float* __restrict__ enc, const short* __restrict__ pebf,
    const short* __restrict__ wt, const float* __restrict__ bpos,
    const float* __restrict__ pew_in, float* __restrict__ pew_out,
    float* __restrict__ ewp,
    const float* __restrict__ pitch, const int* __restrict__ beats,
    const float* __restrict__ wpitch, const float* __restrict__ bpitch,
    const float* __restrict__ embb, const int* __restrict__ flag,
    float* __restrict__ out)
{
    __shared__ __align__(16) short As[64 * 256];
    __shared__ __align__(16) short Bs[64 * 256];

    const int tid = threadIdx.x;
    const int m0 = blockIdx.x * 64;
    const int n0 = blockIdx.y * 64;
    const int r  = tid >> 2, c4 = tid & 3;

    // --- stage A (XOR-swizzled so frag ds_read_b128 is bank-uniform) ---
    if (MODE == 0) {
        const short* ap = pebf + (size_t)(m0 + r) * E_;
#pragma unroll
        for (int j = 0; j < 8; ++j) {
            const int seg = c4 + 4 * j;
            short8 v = *(const short8*)(ap + seg * 8);
            *(short8*)&As[(r * 256 + seg * 8) ^ ((r & 7) << 3)] = v;
        }
    } else {
        const float* ap = enc + (size_t)(m0 + r) * E_;
#pragma unroll
        for (int j = 0; j < 8; ++j) {
            const int seg = c4 + 4 * j;
            float4 e0 = *(const float4*)(ap + seg * 8);
            float4 e1 = *(const float4*)(ap + seg * 8 + 4);
            short8 v;
            v[0] = bf16s(e0.x); v[1] = bf16s(e0.y); v[2] = bf16s(e0.z); v[3] = bf16s(e0.w);
            v[4] = bf16s(e1.x); v[5] = bf16s(e1.y); v[6] = bf16s(e1.z); v[7] = bf16s(e1.w);
            *(short8*)&As[(r * 256 + seg * 8) ^ ((r & 7) << 3)] = v;
        }
    }
    // --- stage B: WT rows n0..n0+64 (already bf16, contiguous k) ---
    {
        const short* bp = wt + (size_t)(n0 + r) * E_;
#pragma unroll
        for (int j = 0; j < 8; ++j) {
            const int seg = c4 + 4 * j;
            short8 v = *(const short8*)(bp + seg * 8);
            *(short8*)&Bs[(r * 256 + seg * 8) ^ ((r & 7) << 3)] = v;
        }
    }
    __syncthreads();

    const int wid = tid >> 6, lane = tid & 63;
    const int q = lane >> 4, c = lane & 15;
    const int wm = (wid >> 1) << 5, wn = (wid & 1) << 5;

    f32x4 acc[2][2] = {{{0.f, 0.f, 0.f, 0.f}, {0.f, 0.f, 0.f, 0.f}},
                       {{0.f, 0.f, 0.f, 0.f}, {0.f, 0.f, 0.f, 0.f}}};

#pragma unroll
    for (int ks = 0; ks < 8; ++ks) {
        const int kidx = ks * 32 + q * 8;
        const int ra0 = wm + c, ra1 = wm + 16 + c;
        const int rb0 = wn + c, rb1 = wn + 16 + c;
        short8 a0 = *(const short8*)&As[(ra0 * 256 + kidx) ^ ((ra0 & 7) << 3)];
        short8 a1 = *(const short8*)&As[(ra1 * 256 + kidx) ^ ((ra1 & 7) << 3)];
        short8 b0 = *(const short8*)&Bs[(rb0 * 256 + kidx) ^ ((rb0 & 7) << 3)];
        short8 b1 = *(const short8*)&Bs[(rb1 * 256 + kidx) ^ ((rb1 & 7) << 3)];
        acc[0][0] = __builtin_amdgcn_mfma_f32_16x16x32_bf16(a0, b0, acc[0][0], 0, 0, 0);
        acc[0][1] = __builtin_amdgcn_mfma_f32_16x16x32_bf16(a0, b1, acc[0][1], 0, 0, 0);
        acc[1][0] = __builtin_amdgcn_mfma_f32_16x16x32_bf16(a1, b0, acc[1][0], 0, 0, 0);
        acc[1][1] = __builtin_amdgcn_mfma_f32_16x16x32_bf16(a1, b1, acc[1][1], 0, 0, 0);
    }

    // --- epilogue (D: row = 4*q + reg, col = lane&15, per verified m89 map) ---
    const int gcol0 = n0 + wn + c;
    const int gcol1 = n0 + wn + 16 + c;

    if (MODE == 0) {
        const float bp0 = bpos[gcol0], bp1 = bpos[gcol1];
#pragma unroll
        for (int mt = 0; mt < 2; ++mt)
#pragma unroll
            for (int rr = 0; rr < 4; ++rr) {
                const int t = m0 + wm + mt * 16 + q * 4 + rr;
                pew_out[(size_t)t * E_ + gcol0] = acc[mt][0][rr] + bp0;
                pew_out[(size_t)t * E_ + gcol1] = acc[mt][1][rr] + bp1;
            }
        return;
    }

    // MODE 1
    const bool fb = (*flag != 0);
    if (!fb) {
        const int bq = m0 >> 9;         // batch (64 | 512)
        const int i0 = m0 & 511;
        const float wpc0 = wpitch[gcol0], wpc1 = wpitch[gcol1];
        const float bpc0 = bpitch[gcol0], bpc1 = bpitch[gcol1];
        const float be00 = embb[gcol0],  be01 = embb[gcol1];
        const float be10 = embb[E_ + gcol0], be11 = embb[E_ + gcol1];
#pragma unroll
        for (int mt = 0; mt < 2; ++mt) {
#pragma unroll
            for (int rr = 0; rr < 4; ++rr) {
                const int lrow = wm + mt * 16 + q * 4 + rr;
                const int gm = m0 + lrow;
                const float* erow = enc + (size_t)gm * E_;
                const float base0 = acc[mt][0][rr] + erow[gcol0];
                const float base1 = acc[mt][1][rr] + erow[gcol1];
                const int tt0 = (i0 + lrow) * 8;
                const size_t prow = (size_t)bq * T_ + tt0;
#pragma unroll
                for (int d = 0; d < 8; ++d) {
                    const float p = pitch[prow + d];
                    const int bt = beats[prow + d];
                    const float bev0 = bt ? be10 : be00;
                    const float bev1 = bt ? be11 : be01;
                    const float pv0 = pew_in[(size_t)(tt0 + d) * E_ + gcol0];
                    const float pv1 = pew_in[(size_t)(tt0 + d) * E_ + gcol1];
                    out[(prow + d) * E_ + gcol0] = base0 + pv0 + p * wpc0 + bpc0 + bev0;
                    out[(prow + d) * E_ + gcol1] = base1 + pv1 + p * wpc1 + bpc1 + bev1;
                }
            }
        }
    } else {
#pragma unroll
        for (int mt = 0; mt < 2; ++mt)
#pragma unroll
            for (int rr = 0; rr < 4; ++rr) {
                const int gm = m0 + wm + mt * 16 + q * 4 + rr;
                const float* erow = enc + (size_t)gm * E_;
                ewp[(size_t)gm * E_ + gcol0] = acc[mt][0][rr] + erow[gcol0];
                ewp[(size_t)gm * E_ + gcol1] = acc[mt][1][rr] + erow[gcol1];
            }
    }
}

// ---------------------------------------------------------------------------
// Conditional final assembly — only when the closed-form idx failed (never
// for this data). Grid-strided so the empty-exit launch is ~free.
__global__ __launch_bounds__(256) void k_final_fb(
    const float* __restrict__ ewp, const float* __restrict__ pew,
    const int* __restrict__ idx, const float* __restrict__ pitch,
    const int* __restrict__ beats, const float* __restrict__ wpitch,
    const float* __restrict__ bpitch, const float* __restrict__ embb,
    const int* __restrict__ flag, float* __restrict__ out)
{
    if (*flag == 0) return;
    const int col = threadIdx.x;
    const float wpc = wpitch[col], bpc = bpitch[col];
    const float be0 = embb[col], be1 = embb[E_ + col];
    for (int row = blockIdx.x; row < B_ * T_; row += gridDim.x) {
        const int b = row / T_, t = row % T_;
        const int i = idx[row];
        const float p = pitch[row];
        const float bev = beats[row] ? be1 : be0;
        out[(size_t)row * E_ + col] = ewp[(size_t)(b * S_ + i) * E_ + col]
                                    + pew[(size_t)t * E_ + col] + p * wpc + bpc + bev;
    }
}

// ---------------------------------------------------------------------------
extern "C" void kernel_launch(void* const* d_in, const int* in_sizes, int n_in,
                              void* d_out, int out_size, void* d_ws, size_t ws_size,
                              hipStream_t stream) {
    const float* enc    = (const float*)d_in[0];
    const int*   align  = (const int*)  d_in[1];
    const int*   text   = (const int*)  d_in[2];
    const float* pitch  = (const float*)d_in[3];
    const int*   beats  = (const int*)  d_in[4];
    const float* wpitch = (const float*)d_in[5];
    const float* bpitch = (const float*)d_in[6];
    const float* embb   = (const float*)d_in[7];
    const float* wpos   = (const float*)d_in[8];
    const float* bpos   = (const float*)d_in[9];
    float* out = (float*)d_out;

    char* ws = (char*)d_ws;
    int*          flag = (int*)          (ws + FLAG_OFF);
    int*          idx  = (int*)          (ws + IDX_OFF);
    short*        wt   = (short*)        (ws + WT_OFF);
    unsigned int* pe2  = (unsigned int*) (ws + PEBF_OFF);
    const short*  pebf = (const short*)  (ws + PEBF_OFF);
    float*        pew  = (float*)        (ws + PEW_OFF);
    float*        ewp  = (float*)        (ws + EWP_OFF);

    hipMemsetAsync(ws + FLAG_OFF, 0, 4, stream);
    hipLaunchKernelGGL(k_prep, dim3(2320), dim3(256), 0, stream,
                       align, text, wpos, idx, flag, wt, pe2);
    hipLaunchKernelGGL(k_fallback, dim3(1), dim3(64), 0, stream,
                       align, text, idx, flag);
    hipLaunchKernelGGL((k_gemm<0>), dim3(T_ / 64, 4), dim3(256), 0, stream,
                       enc, pebf, wt, bpos, pew, pew, ewp,
                       pitch, beats, wpitch, bpitch, embb, flag, out);
    hipLaunchKernelGGL((k_gemm<1>), dim3(M_ENC / 64, 4), dim3(256), 0, stream,
                       enc, pebf, wt, bpos, pew, pew, ewp,
                       pitch, beats, wpitch, bpitch, embb, flag, out);
    hipLaunchKernelGGL(k_final_fb, dim3(512), dim3(256), 0, stream,
                       ewp, pew, idx, pitch, beats, wpitch, bpitch, embb, flag, out);
}

// Round 3
// 36.690 us; speedup vs baseline: 1.5894x; 1.0568x over previous
//
#include <hip/hip_runtime.h>
#include <hip/hip_bf16.h>
#include <math.h>

// Problem constants (fixed by setup_inputs)
constexpr int B_ = 16, S_ = 512, T_ = 4096, E_ = 256;
constexpr int M_ENC = B_ * S_;   // 8192

typedef __attribute__((ext_vector_type(8))) short short8;
typedef __attribute__((ext_vector_type(4))) float f32x4;

// Workspace layout (bytes), total 13 MB
constexpr size_t FLAG_OFF = 0;
constexpr size_t IDX_OFF  = 4096;                 // B*T int32 = 256KB
constexpr size_t WT_OFF   = 512u * 1024;          // 256x256 bf16 (W^T) = 128KB
constexpr size_t PEW_OFF  = 1024u * 1024;         // 4096x256 f32 = 4MB
constexpr size_t EWP_OFF  = 5u * 1024 * 1024;     // 8192x256 f32 = 8MB (fallback only)

// -ln(10000)/256 (round-2 version had a typo in digit 5)
#define NEGC (-0.035977892f)

// packed f32x2 -> bf16x2 (RNE, single v_cvt_pk_bf16_f32)
__device__ __forceinline__ unsigned pk_bf16(float a, float b) {
    __hip_bfloat162 h = __float22bfloat162_rn(make_float2(a, b));
    return *(unsigned*)&h;
}
__device__ __forceinline__ short bf16s(float x) {
    unsigned u = __float_as_uint(x);
    u += 0x7FFFu + ((u >> 16) & 1u);
    return (short)(u >> 16);
}

// ---------------------------------------------------------------------------
// Prep kernel, roles by blockIdx.x:
//  [0,256)   : closed-form aligner idx + parallel validation of the scan
//  [256,272) : W^T -> bf16 (WT[n][k] = W[k][n])
__global__ __launch_bounds__(256) void k_prep(
    const int* __restrict__ align, const int* __restrict__ text,
    const float* __restrict__ W,
    int* __restrict__ idx, int* __restrict__ flag, short* __restrict__ wt)
{
    const int bid = blockIdx.x, tid = threadIdx.x;
    if (bid < 256) {
        const int id = bid * 256 + tid;          // < B*T
        const int b = id / T_, t = id % T_;
        const int cand = t >> 3;                 // DUR = 8
        idx[id] = cand;
        if (t > 0) {
            const int prev = (t - 1) >> 3;
            const int a = align[id];
            const int expct = (a == text[b * S_ + prev]) ? prev : min(prev + 1, S_ - 1);
            if (cand != expct) atomicOr(flag, 1);
        }
    } else {
        const int kb = (bid - 256) * 16;
        short8 v0, v1;
#pragma unroll
        for (int j = 0; j < 8; ++j) v0[j] = bf16s(W[(kb + j) * E_ + tid]);
#pragma unroll
        for (int j = 0; j < 8; ++j) v1[j] = bf16s(W[(kb + 8 + j) * E_ + tid]);
        *(short8*)(wt + tid * E_ + kb)     = v0;
        *(short8*)(wt + tid * E_ + kb + 8) = v1;
    }
}

// Serial fallback (only if validation failed — never for this data)
__global__ void k_fallback(const int* __restrict__ align, const int* __restrict__ text,
                           int* __restrict__ idx, const int* __restrict__ flag) {
    if (*flag == 0) return;
    const int b = threadIdx.x;
    if (b >= B_) return;
    int i = 0;
    idx[b * T_] = 0;
    for (int t = 1; t < T_; ++t) {
        if (align[b * T_ + t] != text[b * S_ + i]) i = min(i + 1, S_ - 1);
        idx[b * T_ + t] = i;
    }
}

// ---------------------------------------------------------------------------
// bf16 MFMA GEMM core. Tile 64(M) x 64(N) x full K=256, 4 waves (2x2 of 32x32),
// then LDS-transpose of the accumulator so the epilogue streams float4 rows.
// MODE 0: A = PE (generated on the fly via __sincosf) -> pew = A@W + b_pos
// MODE 1: A = enc (f32->bf16); epilogue expands each EW row into its 8 output
//         rows: out[b, i*8+d] = enc + acc + pew[t] + pitch*Wp + bp + emb_beats
//         (fallback flag path writes ewp = enc + acc instead)
template <int MODE>
__global__ __launch_bounds__(256) void k_gemm(
    const float* __restrict__ enc, const short* __restrict__ wt,
    const float* __restrict__ bpos,
    const float* __restrict__ pew_in, float* __restrict__ pew_out,
    float* __restrict__ ewp,
    const float* __restrict__ pitch, const int* __restrict__ beats,
    const float* __restrict__ wpitch, const float* __restrict__ bpitch,
    const float* __restrict__ embb, const int* __restrict__ flag,
    float* __restrict__ out)
{
    __shared__ __align__(16) short As[64 * 256];   // 32 KB; reused as f32 ew tile
    __shared__ __align__(16) short Bs[64 * 256];   // 32 KB
    float* ew = (float*)As;                        // [64][68] after MFMA phase

    const int tid = threadIdx.x;
    const int m0 = blockIdx.x * 64;
    const int n0 = blockIdx.y * 64;
    const int r  = tid >> 2, c4 = tid & 3;

    // --- stage A (XOR-swizzled so frag ds_read_b128 is bank-uniform) ---
    if (MODE == 0) {
        const float tf = (float)(m0 + r);
#pragma unroll
        for (int j = 0; j < 8; ++j) {
            const int seg = c4 + 4 * j;
            union { short8 v; unsigned u[4]; } cv;
#pragma unroll
            for (int m = 0; m < 4; ++m) {
                const int j2 = seg * 4 + m;                 // pair index
                const float d = __expf((float)(2 * j2) * NEGC);
                float s, c;
                __sincosf(tf * d, &s, &c);
                cv.u[m] = pk_bf16(s, c);                    // k=2j2 -> sin, k=2j2+1 -> cos
            }
            *(short8*)&As[(r * 256 + seg * 8) ^ ((r & 7) << 3)] = cv.v;
        }
    } else {
        const float* ap = enc + (size_t)(m0 + r) * E_;
#pragma unroll
        for (int j = 0; j < 8; ++j) {
            const int seg = c4 + 4 * j;
            float4 e0 = *(const float4*)(ap + seg * 8);
            float4 e1 = *(const float4*)(ap + seg * 8 + 4);
            union { short8 v; unsigned u[4]; } cv;
            cv.u[0] = pk_bf16(e0.x, e0.y);
            cv.u[1] = pk_bf16(e0.z, e0.w);
            cv.u[2] = pk_bf16(e1.x, e1.y);
            cv.u[3] = pk_bf16(e1.z, e1.w);
            *(short8*)&As[(r * 256 + seg * 8) ^ ((r & 7) << 3)] = cv.v;
        }
    }
    // --- stage B: WT rows n0..n0+64 (already bf16, contiguous k) ---
    {
        const short* bp = wt + (size_t)(n0 + r) * E_;
#pragma unroll
        for (int j = 0; j < 8; ++j) {
            const int seg = c4 + 4 * j;
            short8 v = *(const short8*)(bp + seg * 8);
            *(short8*)&Bs[(r * 256 + seg * 8) ^ ((r & 7) << 3)] = v;
        }
    }
    __syncthreads();

    const int wid = tid >> 6, lane = tid & 63;
    const int q = lane >> 4, c = lane & 15;
    const int wm = (wid >> 1) << 5, wn = (wid & 1) << 5;

    f32x4 acc[2][2] = {{{0.f, 0.f, 0.f, 0.f}, {0.f, 0.f, 0.f, 0.f}},
                       {{0.f, 0.f, 0.f, 0.f}, {0.f, 0.f, 0.f, 0.f}}};

#pragma unroll
    for (int ks = 0; ks < 8; ++ks) {
        const int kidx = ks * 32 + q * 8;
        const int ra0 = wm + c, ra1 = wm + 16 + c;
        const int rb0 = wn + c, rb1 = wn + 16 + c;
        short8 a0 = *(const short8*)&As[(ra0 * 256 + kidx) ^ ((ra0 & 7) << 3)];
        short8 a1 = *(const short8*)&As[(ra1 * 256 + kidx) ^ ((ra1 & 7) << 3)];
        short8 b0 = *(const short8*)&Bs[(rb0 * 256 + kidx) ^ ((rb0 & 7) << 3)];
        short8 b1 = *(const short8*)&Bs[(rb1 * 256 + kidx) ^ ((rb1 & 7) << 3)];
        acc[0][0] = __builtin_amdgcn_mfma_f32_16x16x32_bf16(a0, b0, acc[0][0], 0, 0, 0);
        acc[0][1] = __builtin_amdgcn_mfma_f32_16x16x32_bf16(a0, b1, acc[0][1], 0, 0, 0);
        acc[1][0] = __builtin_amdgcn_mfma_f32_16x16x32_bf16(a1, b0, acc[1][0], 0, 0, 0);
        acc[1][1] = __builtin_amdgcn_mfma_f32_16x16x32_bf16(a1, b1, acc[1][1], 0, 0, 0);
    }

    // --- transpose acc through LDS (D map: row = 4q+reg, col = lane&15) ---
    __syncthreads();   // all As/Bs reads complete; safe to overwrite with ew
#pragma unroll
    for (int mt = 0; mt < 2; ++mt)
#pragma unroll
        for (int nh = 0; nh < 2; ++nh)
#pragma unroll
            for (int rr = 0; rr < 4; ++rr)
                ew[(wm + mt * 16 + q * 4 + rr) * 68 + wn + nh * 16 + c] = acc[mt][nh][rr];
    __syncthreads();

    // --- streaming epilogue: thread -> (rowgrp, col4), 4 row-pairs ---
    const int c4o = tid & 15, rg = tid >> 4;
    const int gc = n0 + 4 * c4o;

    if (MODE == 0) {
        const f32x4 bi = *(const f32x4*)(bpos + gc);
#pragma unroll
        for (int p = 0; p < 4; ++p) {
            const int lrow = rg + p * 16;
            f32x4 v = *(const f32x4*)&ew[lrow * 68 + 4 * c4o];
            v += bi;
            *(f32x4*)(pew_out + (size_t)(m0 + lrow) * E_ + gc) = v;
        }
        return;
    }

    // MODE 1
    const bool fb = (*flag != 0);
    const int bq = m0 >> 9;         // batch
    const int i0 = m0 & 511;        // phone index base
    if (!fb) {
        const f32x4 wp4 = *(const f32x4*)(wpitch + gc);
        const f32x4 bp4 = *(const f32x4*)(bpitch + gc);
        const f32x4 be0 = *(const f32x4*)(embb + gc);
        const f32x4 be1 = *(const f32x4*)(embb + E_ + gc);
#pragma unroll
        for (int p = 0; p < 4; ++p) {
            const int lrow = rg + p * 16;
            const f32x4 ewv = *(const f32x4*)&ew[lrow * 68 + 4 * c4o];
            const f32x4 e4  = *(const f32x4*)(enc + (size_t)(m0 + lrow) * E_ + gc);
            const f32x4 base = ewv + e4 + bp4;
            const int t0 = (i0 + lrow) * 8;
            const size_t prow = (size_t)bq * T_ + t0;
#pragma unroll
            for (int d = 0; d < 8; ++d) {
                const f32x4 pv = *(const f32x4*)(pew_in + (size_t)(t0 + d) * E_ + gc);
                const float pp = pitch[prow + d];
                const f32x4 be = beats[prow + d] ? be1 : be0;
                f32x4 o = base + pv + pp * wp4 + be;
                *(f32x4*)(out + (prow + d) * E_ + gc) = o;
            }
        }
    } else {
#pragma unroll
        for (int p = 0; p < 4; ++p) {
            const int lrow = rg + p * 16;
            const f32x4 ewv = *(const f32x4*)&ew[lrow * 68 + 4 * c4o];
            const f32x4 e4  = *(const f32x4*)(enc + (size_t)(m0 + lrow) * E_ + gc);
            f32x4 o = ewv + e4;
            *(f32x4*)(ewp + (size_t)(m0 + lrow) * E_ + gc) = o;
        }
    }
}

// ---------------------------------------------------------------------------
// Conditional final assembly — only when the closed-form idx failed (never
// for this data). Grid-strided so the empty-exit launch is ~free.
__global__ __launch_bounds__(256) void k_final_fb(
    const float* __restrict__ ewp, const float* __restrict__ pew,
    const int* __restrict__ idx, const float* __restrict__ pitch,
    const int* __restrict__ beats, const float* __restrict__ wpitch,
    const float* __restrict__ bpitch, const float* __restrict__ embb,
    const int* __restrict__ flag, float* __restrict__ out)
{
    if (*flag == 0) return;
    const int col = threadIdx.x;
    const float wpc = wpitch[col], bpc = bpitch[col];
    const float be0 = embb[col], be1 = embb[E_ + col];
    for (int row = blockIdx.x; row < B_ * T_; row += gridDim.x) {
        const int b = row / T_, t = row % T_;
        const int i = idx[row];
        const float p = pitch[row];
        const float bev = beats[row] ? be1 : be0;
        out[(size_t)row * E_ + col] = ewp[(size_t)(b * S_ + i) * E_ + col]
                                    + pew[(size_t)t * E_ + col] + p * wpc + bpc + bev;
    }
}

// ---------------------------------------------------------------------------
extern "C" void kernel_launch(void* const* d_in, const int* in_sizes, int n_in,
                              void* d_out, int out_size, void* d_ws, size_t ws_size,
                              hipStream_t stream) {
    const float* enc    = (const float*)d_in[0];
    const int*   align  = (const int*)  d_in[1];
    const int*   text   = (const int*)  d_in[2];
    const float* pitch  = (const float*)d_in[3];
    const int*   beats  = (const int*)  d_in[4];
    const float* wpitch = (const float*)d_in[5];
    const float* bpitch = (const float*)d_in[6];
    const float* embb   = (const float*)d_in[7];
    const float* wpos   = (const float*)d_in[8];
    const float* bpos   = (const float*)d_in[9];
    float* out = (float*)d_out;

    char* ws = (char*)d_ws;
    int*   flag = (int*)  (ws + FLAG_OFF);
    int*   idx  = (int*)  (ws + IDX_OFF);
    short* wt   = (short*)(ws + WT_OFF);
    float* pew  = (float*)(ws + PEW_OFF);
    float* ewp  = (float*)(ws + EWP_OFF);

    hipMemsetAsync(ws + FLAG_OFF, 0, 4, stream);
    hipLaunchKernelGGL(k_prep, dim3(272), dim3(256), 0, stream,
                       align, text, wpos, idx, flag, wt);
    hipLaunchKernelGGL(k_fallback, dim3(1), dim3(64), 0, stream,
                       align, text, idx, flag);
    hipLaunchKernelGGL((k_gemm<0>), dim3(T_ / 64, 4), dim3(256), 0, stream,
                       enc, wt, bpos, pew, pew, ewp,
                       pitch, beats, wpitch, bpitch, embb, flag, out);
    hipLaunchKernelGGL((k_gemm<1>), dim3(M_ENC / 64, 4), dim3(256), 0, stream,
                       enc, wt, bpos, pew, pew, ewp,
                       pitch, beats, wpitch, bpitch, embb, flag, out);
    hipLaunchKernelGGL(k_final_fb, dim3(512), dim3(256), 0, stream,
                       ewp, pew, idx, pitch, beats, wpitch, bpitch, embb, flag, out);
}

// Round 4
// 27.482 us; speedup vs baseline: 2.1220x; 1.3351x over previous
//
#include <hip/hip_runtime.h>
#include <hip/hip_bf16.h>
#include <math.h>

// Problem constants (fixed by setup_inputs)
constexpr int B_ = 16, S_ = 512, T_ = 4096, E_ = 256;

typedef __attribute__((ext_vector_type(8))) short short8;
typedef __attribute__((ext_vector_type(4))) float f32x4;

// Workspace layout (bytes)
constexpr size_t FLAGS_OFF = 0;          // 256 ints, written unconditionally each call
constexpr size_t WT_OFF    = 4096;       // 256x256 bf16 W^T = 128KB

// -ln(10000)/256
#define NEGC (-0.035977892f)

// packed f32x2 -> bf16x2 (RNE, v_cvt_pk_bf16_f32)
__device__ __forceinline__ unsigned pk_bf16(float a, float b) {
    __hip_bfloat162 h = __float22bfloat162_rn(make_float2(a, b));
    return *(unsigned*)&h;
}
__device__ __forceinline__ short bf16s(float x) {
    unsigned u = __float_as_uint(x);
    u += 0x7FFFu + ((u >> 16) & 1u);
    return (short)(u >> 16);
}

// ---------------------------------------------------------------------------
// Prep: [0,256) aligner-recurrence validation -> flags[bid]; [256,272) W^T bf16.
__global__ __launch_bounds__(256) void k_prep(
    const int* __restrict__ align, const int* __restrict__ text,
    const float* __restrict__ W,
    int* __restrict__ flags, short* __restrict__ wt)
{
    const int bid = blockIdx.x, tid = threadIdx.x;
    if (bid < 256) {
        __shared__ int f;
        if (tid == 0) f = 0;
        __syncthreads();
        const int id = bid * 256 + tid;          // < B*T
        const int b = id / T_, t = id % T_;
        if (t > 0) {
            const int prev = (t - 1) >> 3;       // closed-form idx at t-1 (DUR=8)
            const int a = align[id];
            const int expct = (a == text[b * S_ + prev]) ? prev : min(prev + 1, S_ - 1);
            if ((t >> 3) != expct) f = 1;        // benign race: all writers store 1
        }
        __syncthreads();
        if (tid == 0) flags[bid] = f;
    } else {
        const int kb = (bid - 256) * 16;
        short8 v0, v1;
#pragma unroll
        for (int j = 0; j < 8; ++j) v0[j] = bf16s(W[(kb + j) * E_ + tid]);
#pragma unroll
        for (int j = 0; j < 8; ++j) v1[j] = bf16s(W[(kb + 8 + j) * E_ + tid]);
        *(short8*)(wt + tid * E_ + kb)     = v0;
        *(short8*)(wt + tid * E_ + kb + 8) = v1;
    }
}

// ---------------------------------------------------------------------------
// Fused GEMM. Block = 4 phones x 16 batches x 64 N-cols.
// Phase 1: PEW-slice = PE(32x256, on-the-fly) @ W-slice -> pl (LDS)
// Phase 2: EW tile  = enc(64 gathered rows -> bf16) @ W-slice
// Epilogue: out[b, (i0+j)*8+d] = enc + EW + pl[j*8+d] + pitch*Wp + bp + bpos + emb_beats
__global__ __launch_bounds__(256) void k_fused(
    const float* __restrict__ enc, const short* __restrict__ wt,
    const float* __restrict__ bpos,
    const float* __restrict__ pitch, const int* __restrict__ beats,
    const float* __restrict__ wpitch, const float* __restrict__ bpitch,
    const float* __restrict__ embb, float* __restrict__ out)
{
    __shared__ __align__(16) short As[64 * 256];   // 32KB; later reused as f32 ew[64][68]
    __shared__ __align__(16) short Bs[64 * 256];   // 32KB W^T slice (bf16, k-contig)
    __shared__ float pl[32 * 68];                  // 8.5KB local PEW slice

    const int tid = threadIdx.x;
    const int i0 = blockIdx.x * 4;                 // phone base (0..508)
    const int n0 = blockIdx.y * 64;
    const int t0base = i0 * 8;                     // 32 consecutive t rows

    // ---- stage B: wt rows n0..n0+64 (vector, swizzled) ----
    {
        const int r = tid >> 2, c4 = tid & 3;
        const short* bp = wt + (size_t)(n0 + r) * E_;
#pragma unroll
        for (int j = 0; j < 8; ++j) {
            const int seg = c4 + 4 * j;
            short8 v = *(const short8*)(bp + seg * 8);
            *(short8*)&Bs[(r * 256 + seg * 8) ^ ((r & 7) << 3)] = v;
        }
    }
    // ---- stage A = PE rows 0..31 (on-the-fly sincos) ----
    {
        const int r = tid >> 3;                    // 0..31
        const int c8 = tid & 7;
        const float tf = (float)(t0base + r);
#pragma unroll
        for (int jj = 0; jj < 4; ++jj) {
            const int seg = c8 * 4 + jj;           // 0..31
            union { short8 v; unsigned u[4]; } cv;
#pragma unroll
            for (int m = 0; m < 4; ++m) {
                const int j2 = seg * 4 + m;
                const float d = __expf((float)(2 * j2) * NEGC);
                float s, c;
                __sincosf(tf * d, &s, &c);
                cv.u[m] = pk_bf16(s, c);
            }
            *(short8*)&As[(r * 256 + seg * 8) ^ ((r & 7) << 3)] = cv.v;
        }
    }
    __syncthreads();

    const int wid = tid >> 6, lane = tid & 63;
    const int q = lane >> 4, c = lane & 15;

    // ---- phase 1 MFMA: 32x64 PEW slice; wave w: rows (w&1)*16, cols (w>>1)*32 ----
    {
        const int ar = (wid & 1) * 16 + c;
        const int br0 = (wid >> 1) * 32 + c, br1 = br0 + 16;
        f32x4 p0 = {0.f, 0.f, 0.f, 0.f}, p1 = {0.f, 0.f, 0.f, 0.f};
#pragma unroll
        for (int ks = 0; ks < 8; ++ks) {
            const int kidx = ks * 32 + q * 8;
            short8 a  = *(const short8*)&As[(ar * 256 + kidx) ^ ((ar & 7) << 3)];
            short8 b0 = *(const short8*)&Bs[(br0 * 256 + kidx) ^ ((br0 & 7) << 3)];
            short8 b1 = *(const short8*)&Bs[(br1 * 256 + kidx) ^ ((br1 & 7) << 3)];
            p0 = __builtin_amdgcn_mfma_f32_16x16x32_bf16(a, b0, p0, 0, 0, 0);
            p1 = __builtin_amdgcn_mfma_f32_16x16x32_bf16(a, b1, p1, 0, 0, 0);
        }
#pragma unroll
        for (int rr = 0; rr < 4; ++rr) {
            const int prw = (wid & 1) * 16 + q * 4 + rr;
            pl[prw * 68 + (wid >> 1) * 32 + c]      = p0[rr];
            pl[prw * 68 + (wid >> 1) * 32 + 16 + c] = p1[rr];
        }
    }
    __syncthreads();   // As reads done; pl visible

    // ---- stage A = enc tile (row r: b = r>>2, j = r&3 -> enc[b*512 + i0 + j]) ----
    {
        const int r = tid >> 2, c4 = tid & 3;
        const float* ap = enc + (size_t)((r >> 2) * S_ + i0 + (r & 3)) * E_;
#pragma unroll
        for (int jj = 0; jj < 8; ++jj) {
            const int seg = c4 + 4 * jj;
            float4 e0 = *(const float4*)(ap + seg * 8);
            float4 e1 = *(const float4*)(ap + seg * 8 + 4);
            union { short8 v; unsigned u[4]; } cv;
            cv.u[0] = pk_bf16(e0.x, e0.y);
            cv.u[1] = pk_bf16(e0.z, e0.w);
            cv.u[2] = pk_bf16(e1.x, e1.y);
            cv.u[3] = pk_bf16(e1.z, e1.w);
            *(short8*)&As[(r * 256 + seg * 8) ^ ((r & 7) << 3)] = cv.v;
        }
    }
    __syncthreads();

    // ---- phase 2 MFMA: 64x64, wave = 2x2 of 16x16-pairs (32x32 quadrant) ----
    const int wm = (wid >> 1) << 5, wn = (wid & 1) << 5;
    f32x4 acc[2][2] = {{{0.f, 0.f, 0.f, 0.f}, {0.f, 0.f, 0.f, 0.f}},
                       {{0.f, 0.f, 0.f, 0.f}, {0.f, 0.f, 0.f, 0.f}}};
#pragma unroll
    for (int ks = 0; ks < 8; ++ks) {
        const int kidx = ks * 32 + q * 8;
        const int ra0 = wm + c, ra1 = wm + 16 + c;
        const int rb0 = wn + c, rb1 = wn + 16 + c;
        short8 a0 = *(const short8*)&As[(ra0 * 256 + kidx) ^ ((ra0 & 7) << 3)];
        short8 a1 = *(const short8*)&As[(ra1 * 256 + kidx) ^ ((ra1 & 7) << 3)];
        short8 b0 = *(const short8*)&Bs[(rb0 * 256 + kidx) ^ ((rb0 & 7) << 3)];
        short8 b1 = *(const short8*)&Bs[(rb1 * 256 + kidx) ^ ((rb1 & 7) << 3)];
        acc[0][0] = __builtin_amdgcn_mfma_f32_16x16x32_bf16(a0, b0, acc[0][0], 0, 0, 0);
        acc[0][1] = __builtin_amdgcn_mfma_f32_16x16x32_bf16(a0, b1, acc[0][1], 0, 0, 0);
        acc[1][0] = __builtin_amdgcn_mfma_f32_16x16x32_bf16(a1, b0, acc[1][0], 0, 0, 0);
        acc[1][1] = __builtin_amdgcn_mfma_f32_16x16x32_bf16(a1, b1, acc[1][1], 0, 0, 0);
    }

    // ---- transpose acc through LDS (D map: row = 4q+reg, col = lane&15) ----
    __syncthreads();   // all As reads complete; safe to overwrite with ew
    float* ew = (float*)As;
#pragma unroll
    for (int mt = 0; mt < 2; ++mt)
#pragma unroll
        for (int nh = 0; nh < 2; ++nh)
#pragma unroll
            for (int rr = 0; rr < 4; ++rr)
                ew[(wm + mt * 16 + q * 4 + rr) * 68 + wn + nh * 16 + c] = acc[mt][nh][rr];
    __syncthreads();

    // ---- epilogue: thread (rg, c4o); j fixed per thread, batch varies with p ----
    const int c4o = tid & 15, rg = tid >> 4;
    const int gc = n0 + 4 * c4o;
    const int j = rg & 3;
    const int t0 = t0base + j * 8;

    f32x4 pv[8];
#pragma unroll
    for (int d = 0; d < 8; ++d)
        pv[d] = *(const f32x4*)&pl[(j * 8 + d) * 68 + 4 * c4o];

    const f32x4 wp4 = *(const f32x4*)(wpitch + gc);
    const f32x4 cst = *(const f32x4*)(bpitch + gc) + *(const f32x4*)(bpos + gc);
    const f32x4 be0 = *(const f32x4*)(embb + gc);
    const f32x4 be1 = *(const f32x4*)(embb + E_ + gc);

#pragma unroll
    for (int p = 0; p < 4; ++p) {
        const int lrow = rg + p * 16;
        const int bq = lrow >> 2;
        const f32x4 ewv = *(const f32x4*)&ew[lrow * 68 + 4 * c4o];
        const f32x4 e4  = *(const f32x4*)(enc + (size_t)(bq * S_ + i0 + j) * E_ + gc);
        const f32x4 base = ewv + e4 + cst;
        const size_t prow = (size_t)bq * T_ + t0;
        const float4 pi0 = *(const float4*)(pitch + prow);
        const float4 pi1 = *(const float4*)(pitch + prow + 4);
        const int4  bt0 = *(const int4*)(beats + prow);
        const int4  bt1 = *(const int4*)(beats + prow + 4);
        const float pp[8] = {pi0.x, pi0.y, pi0.z, pi0.w, pi1.x, pi1.y, pi1.z, pi1.w};
        const int   bb[8] = {bt0.x, bt0.y, bt0.z, bt0.w, bt1.x, bt1.y, bt1.z, bt1.w};
#pragma unroll
        for (int d = 0; d < 8; ++d) {
            const f32x4 be = bb[d] ? be1 : be0;
            f32x4 o = base + pv[d] + pp[d] * wp4 + be;
            *(f32x4*)(out + (prow + d) * E_ + gc) = o;
        }
    }
}

// ---------------------------------------------------------------------------
// Fallback: only if the closed-form idx failed validation (never for this
// data). Full fp32 recompute, slow but correct; instant exit otherwise.
__global__ __launch_bounds__(256) void k_fb(
    const float* __restrict__ enc, const int* __restrict__ align,
    const int* __restrict__ text, const float* __restrict__ pitch,
    const int* __restrict__ beats, const float* __restrict__ wpitch,
    const float* __restrict__ bpitch, const float* __restrict__ embb,
    const float* __restrict__ W, const float* __restrict__ bpos,
    const int* __restrict__ flags, float* __restrict__ out)
{
    __shared__ int f4[4];
    __shared__ int idx[T_];
    const int tid = threadIdx.x;
    {
        const int v = flags[tid];
        const bool any = __any(v != 0);
        if ((tid & 63) == 0) f4[tid >> 6] = any ? 1 : 0;
    }
    __syncthreads();
    if (!(f4[0] | f4[1] | f4[2] | f4[3])) return;

    const int b = blockIdx.x;     // 16 blocks
    if (tid == 0) {
        int i = 0;
        idx[0] = 0;
        for (int t = 1; t < T_; ++t) {
            if (align[b * T_ + t] != text[b * S_ + i]) i = min(i + 1, S_ - 1);
            idx[t] = i;
        }
    }
    __syncthreads();
    const int col = tid;
    for (int t = 0; t < T_; ++t) {
        const int i = idx[t];
        const float* erow = enc + (size_t)(b * S_ + i) * E_;
        float acc = 0.f;
        for (int k = 0; k < E_; ++k) {
            const int j2 = k >> 1;
            const float d = __expf((float)(2 * j2) * NEGC);
            float s, cc;
            __sincosf((float)t * d, &s, &cc);
            const float pe = (k & 1) ? cc : s;
            acc += (erow[k] + pe) * W[k * E_ + col];
        }
        const float p = pitch[b * T_ + t];
        const float be = beats[b * T_ + t] ? embb[E_ + col] : embb[col];
        out[(size_t)(b * T_ + t) * E_ + col] =
            erow[col] + acc + bpos[col] + p * wpitch[col] + bpitch[col] + be;
    }
}

// ---------------------------------------------------------------------------
extern "C" void kernel_launch(void* const* d_in, const int* in_sizes, int n_in,
                              void* d_out, int out_size, void* d_ws, size_t ws_size,
                              hipStream_t stream) {
    const float* enc    = (const float*)d_in[0];
    const int*   align  = (const int*)  d_in[1];
    const int*   text   = (const int*)  d_in[2];
    const float* pitch  = (const float*)d_in[3];
    const int*   beats  = (const int*)  d_in[4];
    const float* wpitch = (const float*)d_in[5];
    const float* bpitch = (const float*)d_in[6];
    const float* embb   = (const float*)d_in[7];
    const float* wpos   = (const float*)d_in[8];
    const float* bpos   = (const float*)d_in[9];
    float* out = (float*)d_out;

    char* ws = (char*)d_ws;
    int*   flags = (int*)  (ws + FLAGS_OFF);
    short* wt    = (short*)(ws + WT_OFF);

    hipLaunchKernelGGL(k_prep, dim3(272), dim3(256), 0, stream,
                       align, text, wpos, flags, wt);
    hipLaunchKernelGGL(k_fused, dim3(S_ / 4, 4), dim3(256), 0, stream,
                       enc, wt, bpos, pitch, beats, wpitch, bpitch, embb, out);
    hipLaunchKernelGGL(k_fb, dim3(B_), dim3(256), 0, stream,
                       enc, align, text, pitch, beats, wpitch, bpitch, embb,
                       wpos, bpos, flags, out);
}

// Round 5
// 26.330 us; speedup vs baseline: 2.2149x; 1.0438x over previous
//
#include <hip/hip_runtime.h>
#include <hip/hip_bf16.h>
#include <math.h>

// Problem constants (fixed by setup_inputs)
constexpr int B_ = 16, S_ = 512, T_ = 4096, E_ = 256;

typedef __attribute__((ext_vector_type(8))) short short8;
typedef __attribute__((ext_vector_type(4))) float f32x4;

// Workspace layout (bytes)
constexpr size_t FLAGS_OFF = 0;          // 48 ints, written unconditionally each call
constexpr size_t WT_OFF    = 4096;       // 256x256 bf16 W^T = 128KB

// -ln(10000)/256
#define NEGC (-0.035977892f)

__device__ __forceinline__ unsigned pk_bf16(float a, float b) {
    __hip_bfloat162 h = __float22bfloat162_rn(make_float2(a, b));
    return *(unsigned*)&h;
}
__device__ __forceinline__ short bf16s(float x) {
    unsigned u = __float_as_uint(x);
    u += 0x7FFFu + ((u >> 16) & 1u);
    return (short)(u >> 16);
}

// ---------------------------------------------------------------------------
// Prep: [0,32) aligner-recurrence validation (8 ids/thread, int4) -> flags[bid];
//       [32,48) W^T -> bf16.
__global__ __launch_bounds__(256) void k_prep(
    const int* __restrict__ align, const int* __restrict__ text,
    const float* __restrict__ W,
    int* __restrict__ flags, short* __restrict__ wt)
{
    const int bid = blockIdx.x, tid = threadIdx.x;
    if (bid < 32) {
        __shared__ int f;
        if (tid == 0) f = 0;
        __syncthreads();
        const int base = (bid * 256 + tid) * 8;
        const int4 a0 = *(const int4*)(align + base);
        const int4 a1 = *(const int4*)(align + base + 4);
        const int av[8] = {a0.x, a0.y, a0.z, a0.w, a1.x, a1.y, a1.z, a1.w};
        int bad = 0;
#pragma unroll
        for (int m = 0; m < 8; ++m) {
            const int id = base + m;
            const int t = id & (T_ - 1), b = id >> 12;
            if (t > 0) {
                const int prev = (t - 1) >> 3;
                const int expct = (av[m] == text[b * S_ + prev]) ? prev : min(prev + 1, S_ - 1);
                if ((t >> 3) != expct) bad = 1;
            }
        }
        if (bad) f = 1;                  // benign race: all writers store 1
        __syncthreads();
        if (tid == 0) flags[bid] = f;
    } else {
        const int kb = (bid - 32) * 16;
        short8 v0, v1;
#pragma unroll
        for (int j = 0; j < 8; ++j) v0[j] = bf16s(W[(kb + j) * E_ + tid]);
#pragma unroll
        for (int j = 0; j < 8; ++j) v1[j] = bf16s(W[(kb + 8 + j) * E_ + tid]);
        *(short8*)(wt + tid * E_ + kb)     = v0;
        *(short8*)(wt + tid * E_ + kb + 8) = v1;
    }
}

// ---------------------------------------------------------------------------
// Fused GEMM. Block = 4 phones x 16 batches x 64 N-cols.
// Reads flags (written by k_prep, stream-ordered); if any set, takes the
// fp32 exact slow path (never for this data).
__global__ __launch_bounds__(256) void k_fused(
    const float* __restrict__ enc, const short* __restrict__ wt,
    const float* __restrict__ bpos,
    const float* __restrict__ pitch, const int* __restrict__ beats,
    const float* __restrict__ wpitch, const float* __restrict__ bpitch,
    const float* __restrict__ embb,
    const float* __restrict__ W, const int* __restrict__ align,
    const int* __restrict__ text, const int* __restrict__ flags,
    float* __restrict__ out)
{
    __shared__ __align__(16) short As[64 * 256];   // 32KB; later reused as f32 ew[64][68]
    __shared__ __align__(16) short Bs[64 * 256];   // 32KB
    __shared__ float pl[32 * 68];                  // 8.5KB local PEW slice
    __shared__ int idxl[16][32];                   // slow path only

    const int tid = threadIdx.x;
    const int i0 = blockIdx.x * 4;                 // phone base
    const int n0 = blockIdx.y * 64;
    const int t0base = i0 * 8;

    // ---- fallback flag (wave-uniform: every wave reads all 32 flags) ----
    const bool fb = __any(flags[tid & 31] != 0);
    if (fb) {
        // ---- exact fp32 slow path (never taken for this data) ----
        if (tid < 16) {
            int i = 0;
            const int b = tid;
            if (i0 == 0) idxl[b][0] = 0;
            const int tmax = t0base + 32;
            for (int t = 1; t < tmax; ++t) {
                if (align[b * T_ + t] != text[b * S_ + i]) i = min(i + 1, S_ - 1);
                if (t >= t0base) idxl[b][t - t0base] = i;
            }
        }
        __syncthreads();
        for (int r = tid; r < 512; r += 256) {
            const int bq = r >> 5, tt = r & 31;
            const int t = t0base + tt;
            const int i = idxl[bq][tt];
            const float* erow = enc + (size_t)(bq * S_ + i) * E_;
            const float p = pitch[(size_t)bq * T_ + t];
            const int bt = beats[(size_t)bq * T_ + t];
            for (int cc = 0; cc < 64; ++cc) {
                const int col = n0 + cc;
                float acc = 0.f;
                for (int k2 = 0; k2 < 128; ++k2) {
                    const float d = __expf((float)(2 * k2) * NEGC);
                    float s, c;
                    __sincosf((float)t * d, &s, &c);
                    acc += (erow[2 * k2] + s) * W[(2 * k2) * E_ + col]
                         + (erow[2 * k2 + 1] + c) * W[(2 * k2 + 1) * E_ + col];
                }
                out[((size_t)bq * T_ + t) * E_ + col] =
                    erow[col] + acc + bpos[col] + p * wpitch[col] + bpitch[col]
                    + (bt ? embb[E_ + col] : embb[col]);
            }
        }
        return;
    }

    // ---- pre-issue epilogue globals (latency hidden under staging/MFMA) ----
    const int c4o = tid & 15, rg = tid >> 4;
    const int gc = n0 + 4 * c4o;
    const int j = rg & 3;
    const int t0 = t0base + j * 8;
    float4 pi0[4], pi1[4]; int4 bt0[4], bt1[4]; f32x4 e4[4];
#pragma unroll
    for (int p = 0; p < 4; ++p) {
        const int bq = (rg + p * 16) >> 2;
        const size_t prow = (size_t)bq * T_ + t0;
        pi0[p] = *(const float4*)(pitch + prow);
        pi1[p] = *(const float4*)(pitch + prow + 4);
        bt0[p] = *(const int4*)(beats + prow);
        bt1[p] = *(const int4*)(beats + prow + 4);
        e4[p]  = *(const f32x4*)(enc + (size_t)(bq * S_ + i0 + j) * E_ + gc);
    }
    const f32x4 wp4 = *(const f32x4*)(wpitch + gc);
    const f32x4 cst = *(const f32x4*)(bpitch + gc) + *(const f32x4*)(bpos + gc);
    const f32x4 be0 = *(const f32x4*)(embb + gc);
    const f32x4 be1 = *(const f32x4*)(embb + E_ + gc);

    // ---- stage B: wt rows n0..n0+64 (vector, swizzled) ----
    {
        const int r = tid >> 2, c4 = tid & 3;
        const short* bp = wt + (size_t)(n0 + r) * E_;
#pragma unroll
        for (int jj = 0; jj < 8; ++jj) {
            const int seg = c4 + 4 * jj;
            short8 v = *(const short8*)(bp + seg * 8);
            *(short8*)&Bs[(r * 256 + seg * 8) ^ ((r & 7) << 3)] = v;
        }
    }
    // ---- stage A = PE rows (on-the-fly sincos) ----
    {
        const int r = tid >> 3;                    // 0..31
        const int c8 = tid & 7;
        const float tf = (float)(t0base + r);
#pragma unroll
        for (int jj = 0; jj < 4; ++jj) {
            const int seg = c8 * 4 + jj;
            union { short8 v; unsigned u[4]; } cv;
#pragma unroll
            for (int m = 0; m < 4; ++m) {
                const int j2 = seg * 4 + m;
                const float d = __expf((float)(2 * j2) * NEGC);
                float s, c;
                __sincosf(tf * d, &s, &c);
                cv.u[m] = pk_bf16(s, c);
            }
            *(short8*)&As[(r * 256 + seg * 8) ^ ((r & 7) << 3)] = cv.v;
        }
    }
    __syncthreads();

    const int wid = tid >> 6, lane = tid & 63;
    const int q = lane >> 4, c = lane & 15;

    // ---- phase 1 MFMA: 32x64 PEW slice ----
    {
        const int ar = (wid & 1) * 16 + c;
        const int br0 = (wid >> 1) * 32 + c, br1 = br0 + 16;
        f32x4 p0 = {0.f, 0.f, 0.f, 0.f}, p1 = {0.f, 0.f, 0.f, 0.f};
#pragma unroll
        for (int ks = 0; ks < 8; ++ks) {
            const int kidx = ks * 32 + q * 8;
            short8 a  = *(const short8*)&As[(ar * 256 + kidx) ^ ((ar & 7) << 3)];
            short8 b0 = *(const short8*)&Bs[(br0 * 256 + kidx) ^ ((br0 & 7) << 3)];
            short8 b1 = *(const short8*)&Bs[(br1 * 256 + kidx) ^ ((br1 & 7) << 3)];
            p0 = __builtin_amdgcn_mfma_f32_16x16x32_bf16(a, b0, p0, 0, 0, 0);
            p1 = __builtin_amdgcn_mfma_f32_16x16x32_bf16(a, b1, p1, 0, 0, 0);
        }
#pragma unroll
        for (int rr = 0; rr < 4; ++rr) {
            const int prw = (wid & 1) * 16 + q * 4 + rr;
            pl[prw * 68 + (wid >> 1) * 32 + c]      = p0[rr];
            pl[prw * 68 + (wid >> 1) * 32 + 16 + c] = p1[rr];
        }
    }
    __syncthreads();   // As reads done; pl visible

    // ---- stage A = enc tile; pre-read pv from pl in parallel ----
    f32x4 pv[8];
    {
        const int r = tid >> 2, c4 = tid & 3;
        const float* ap = enc + (size_t)((r >> 2) * S_ + i0 + (r & 3)) * E_;
#pragma unroll
        for (int jj = 0; jj < 8; ++jj) {
            const int seg = c4 + 4 * jj;
            float4 f0 = *(const float4*)(ap + seg * 8);
            float4 f1 = *(const float4*)(ap + seg * 8 + 4);
            union { short8 v; unsigned u[4]; } cv;
            cv.u[0] = pk_bf16(f0.x, f0.y);
            cv.u[1] = pk_bf16(f0.z, f0.w);
            cv.u[2] = pk_bf16(f1.x, f1.y);
            cv.u[3] = pk_bf16(f1.z, f1.w);
            *(short8*)&As[(r * 256 + seg * 8) ^ ((r & 7) << 3)] = cv.v;
        }
#pragma unroll
        for (int d = 0; d < 8; ++d)
            pv[d] = *(const f32x4*)&pl[(j * 8 + d) * 68 + 4 * c4o];
    }
    __syncthreads();

    // ---- phase 2 MFMA: 64x64 ----
    const int wm = (wid >> 1) << 5, wn = (wid & 1) << 5;
    f32x4 acc[2][2] = {{{0.f, 0.f, 0.f, 0.f}, {0.f, 0.f, 0.f, 0.f}},
                       {{0.f, 0.f, 0.f, 0.f}, {0.f, 0.f, 0.f, 0.f}}};
#pragma unroll
    for (int ks = 0; ks < 8; ++ks) {
        const int kidx = ks * 32 + q * 8;
        const int ra0 = wm + c, ra1 = wm + 16 + c;
        const int rb0 = wn + c, rb1 = wn + 16 + c;
        short8 a0 = *(const short8*)&As[(ra0 * 256 + kidx) ^ ((ra0 & 7) << 3)];
        short8 a1 = *(const short8*)&As[(ra1 * 256 + kidx) ^ ((ra1 & 7) << 3)];
        short8 b0 = *(const short8*)&Bs[(rb0 * 256 + kidx) ^ ((rb0 & 7) << 3)];
        short8 b1 = *(const short8*)&Bs[(rb1 * 256 + kidx) ^ ((rb1 & 7) << 3)];
        acc[0][0] = __builtin_amdgcn_mfma_f32_16x16x32_bf16(a0, b0, acc[0][0], 0, 0, 0);
        acc[0][1] = __builtin_amdgcn_mfma_f32_16x16x32_bf16(a0, b1, acc[0][1], 0, 0, 0);
        acc[1][0] = __builtin_amdgcn_mfma_f32_16x16x32_bf16(a1, b0, acc[1][0], 0, 0, 0);
        acc[1][1] = __builtin_amdgcn_mfma_f32_16x16x32_bf16(a1, b1, acc[1][1], 0, 0, 0);
    }

    // ---- transpose acc through LDS (D map: row = 4q+reg, col = lane&15) ----
    __syncthreads();
    float* ew = (float*)As;
#pragma unroll
    for (int mt = 0; mt < 2; ++mt)
#pragma unroll
        for (int nh = 0; nh < 2; ++nh)
#pragma unroll
            for (int rr = 0; rr < 4; ++rr)
                ew[(wm + mt * 16 + q * 4 + rr) * 68 + wn + nh * 16 + c] = acc[mt][nh][rr];
    __syncthreads();

    // ---- epilogue: all globals already in regs; nontemporal stores ----
#pragma unroll
    for (int p = 0; p < 4; ++p) {
        const int lrow = rg + p * 16;
        const int bq = lrow >> 2;
        const f32x4 ewv = *(const f32x4*)&ew[lrow * 68 + 4 * c4o];
        const f32x4 base = ewv + e4[p] + cst;
        const size_t prow = (size_t)bq * T_ + t0;
        const float pp[8] = {pi0[p].x, pi0[p].y, pi0[p].z, pi0[p].w,
                             pi1[p].x, pi1[p].y, pi1[p].z, pi1[p].w};
        const int   bb[8] = {bt0[p].x, bt0[p].y, bt0[p].z, bt0[p].w,
                             bt1[p].x, bt1[p].y, bt1[p].z, bt1[p].w};
#pragma unroll
        for (int d = 0; d < 8; ++d) {
            const f32x4 be = bb[d] ? be1 : be0;
            f32x4 o = base + pv[d] + pp[d] * wp4 + be;
            __builtin_nontemporal_store(o, (f32x4*)(out + (prow + d) * E_ + gc));
        }
    }
}

// ---------------------------------------------------------------------------
extern "C" void kernel_launch(void* const* d_in, const int* in_sizes, int n_in,
                              void* d_out, int out_size, void* d_ws, size_t ws_size,
                              hipStream_t stream) {
    const float* enc    = (const float*)d_in[0];
    const int*   align  = (const int*)  d_in[1];
    const int*   text   = (const int*)  d_in[2];
    const float* pitch  = (const float*)d_in[3];
    const int*   beats  = (const int*)  d_in[4];
    const float* wpitch = (const float*)d_in[5];
    const float* bpitch = (const float*)d_in[6];
    const float* embb   = (const float*)d_in[7];
    const float* wpos   = (const float*)d_in[8];
    const float* bpos   = (const float*)d_in[9];
    float* out = (float*)d_out;

    char* ws = (char*)d_ws;
    int*   flags = (int*)  (ws + FLAGS_OFF);
    short* wt    = (short*)(ws + WT_OFF);

    hipLaunchKernelGGL(k_prep, dim3(48), dim3(256), 0, stream,
                       align, text, wpos, flags, wt);
    hipLaunchKernelGGL(k_fused, dim3(S_ / 4, 4), dim3(256), 0, stream,
                       enc, wt, bpos, pitch, beats, wpitch, bpitch, embb,
                       wpos, align, text, flags, out);
}